// Round 18
// baseline (198.576 us; speedup 1.0000x reference)
//
#include <hip/hip_runtime.h>
#include <stdint.h>

#define NPTS 8192
#define KNN  32
#define WAVES 8
#define BTHR (WAVES*64)
#define CAP  512
#define K2BLK 64

// grid (G=24: cell 0.5 -> rectangle ~1000 candidates vs 1760 at G=16)
#define G     24
#define NCELL (G*G*G)        // 13824 per batch
#define TOTC  (2*NCELL)      // 27648 both batches
#define SCITEMS 27           // scan items per thread (1024*27 = 27648)
#define GLO   (-6.0f)
#define GINV  (2.0f)         // 1/0.5 exact

// ---------------- f32 LAPACK constants (SLAMCH) ----------------
#define EPSF    5.9604645e-08f
#define EPS2F   3.5527137e-15f
#define SAFMINF 1.17549435e-38f
#define SAFMAXF 8.5070592e+37f
#define RTMINF  1.0842022e-19f
#define RTMAXF  9.2233720e+18f

__device__ __forceinline__ float fsignf(float a, float b) {
  return __builtin_copysignf(fabsf(a), b);
}

__device__ __forceinline__ float slapy2f(float x, float y) {
  float xa = fabsf(x), ya = fabsf(y);
  float w = fmaxf(xa, ya), z = fminf(xa, ya);
  if (z == 0.0f) return w;
  float t = __fdiv_rn(z, w);
  return __fmul_rn(w, __fsqrt_rn(__fadd_rn(1.0f, __fmul_rn(t, t))));
}

// LAPACK >= 3.10 slartg
__device__ __forceinline__ void slartgf(float f, float g, float& c, float& s, float& r) {
  if (g == 0.0f)      { c = 1.0f; s = 0.0f; r = f; }
  else if (f == 0.0f) { c = 0.0f; s = __builtin_copysignf(1.0f, g); r = fabsf(g); }
  else {
    float f1 = fabsf(f), g1 = fabsf(g);
    if (f1 > RTMINF && f1 < RTMAXF && g1 > RTMINF && g1 < RTMAXF) {
      float d = __fsqrt_rn(__fadd_rn(__fmul_rn(f, f), __fmul_rn(g, g)));
      c = __fdiv_rn(f1, d);
      r = __builtin_copysignf(d, f);
      s = __fdiv_rn(g, r);
    } else {
      float u  = fminf(SAFMAXF, fmaxf(SAFMINF, fmaxf(f1, g1)));
      float fs = __fdiv_rn(f, u), gs = __fdiv_rn(g, u);
      float d  = __fsqrt_rn(__fadd_rn(__fmul_rn(fs, fs), __fmul_rn(gs, gs)));
      c = __fdiv_rn(fabsf(fs), d);
      r = __builtin_copysignf(d, f);
      s = __fdiv_rn(gs, r);
      r = __fmul_rn(r, u);
    }
  }
}

__device__ void slaev2f(float a, float b, float c,
                        float& rt1, float& rt2, float& cs1, float& sn1) {
  float sm = __fadd_rn(a, c), df = __fsub_rn(a, c);
  float adf = fabsf(df), tb = __fadd_rn(b, b), ab = fabsf(tb);
  float acmx, acmn;
  if (fabsf(a) > fabsf(c)) { acmx = a; acmn = c; } else { acmx = c; acmn = a; }
  float rt;
  if (adf > ab) {
    float t = __fdiv_rn(ab, adf);
    rt = __fmul_rn(adf, __fsqrt_rn(__fadd_rn(1.0f, __fmul_rn(t, t))));
  } else if (adf < ab) {
    float t = __fdiv_rn(adf, ab);
    rt = __fmul_rn(ab, __fsqrt_rn(__fadd_rn(1.0f, __fmul_rn(t, t))));
  } else {
    rt = __fmul_rn(ab, __fsqrt_rn(2.0f));
  }
  int sgn1;
  if (sm < 0.0f) {
    rt1 = __fmul_rn(0.5f, __fsub_rn(sm, rt)); sgn1 = -1;
    rt2 = __fsub_rn(__fmul_rn(__fdiv_rn(acmx, rt1), acmn), __fmul_rn(__fdiv_rn(b, rt1), b));
  } else if (sm > 0.0f) {
    rt1 = __fmul_rn(0.5f, __fadd_rn(sm, rt)); sgn1 = 1;
    rt2 = __fsub_rn(__fmul_rn(__fdiv_rn(acmx, rt1), acmn), __fmul_rn(__fdiv_rn(b, rt1), b));
  } else {
    rt1 = __fmul_rn(0.5f, rt); rt2 = -rt1; sgn1 = 1;
  }
  float cs; int sgn2;
  if (df >= 0.0f) { cs = __fadd_rn(df, rt); sgn2 = 1; }
  else            { cs = __fsub_rn(df, rt); sgn2 = -1; }
  float acs = fabsf(cs);
  if (acs > ab) {
    float ct = __fdiv_rn(-tb, cs);
    sn1 = __fdiv_rn(1.0f, __fsqrt_rn(__fadd_rn(1.0f, __fmul_rn(ct, ct))));
    cs1 = __fmul_rn(ct, sn1);
  } else {
    if (ab == 0.0f) { cs1 = 1.0f; sn1 = 0.0f; }
    else {
      float tn = __fdiv_rn(-cs, tb);
      cs1 = __fdiv_rn(1.0f, __fsqrt_rn(__fadd_rn(1.0f, __fmul_rn(tn, tn))));
      sn1 = __fmul_rn(tn, cs1);
    }
  }
  if (sgn1 == sgn2) { float tn = cs1; cs1 = -sn1; sn1 = tn; }
}

// Per-lane eigensolver state in LDS, strided by K2BLK (round-5-verified layout).
#define ZZ(i,j) base[((i)*3+(j))*K2BLK]
#define DD(i)   base[(9+(i))*K2BLK]
#define EE(i)   base[(12+(i))*K2BLK]
#define CW(i)   base[(14+(i))*K2BLK]
#define SW(i)   base[(16+(i))*K2BLK]

__device__ void steqr3f(float* base) {
  const int nmaxit = 90;
  int jtot = 0;
  int l1 = 0;
  for (int outer = 0; outer < 6; ++outer) {
    if (l1 > 2) break;
    if (l1 > 0) EE(l1 - 1) = 0.0f;
    int m = 2;
    for (int mm = l1; mm <= 1; ++mm) {
      float tst = fabsf(EE(mm));
      if (tst == 0.0f) { m = mm; break; }
      float thr = __fmul_rn(__fmul_rn(__fsqrt_rn(fabsf(DD(mm))), __fsqrt_rn(fabsf(DD(mm + 1)))), EPSF);
      if (tst <= thr) { EE(mm) = 0.0f; m = mm; break; }
    }
    int l = l1;
    int lend = m;
    l1 = m + 1;
    if (lend == l) continue;
    if (fabsf(DD(lend)) < fabsf(DD(l))) { int t = l; l = lend; lend = t; }
    if (lend > l) {
      for (int it = 0; it < 120; ++it) {
        int m2 = lend;
        if (l != lend) {
          for (int mm = l; mm <= lend - 1; ++mm) {
            float tst = __fmul_rn(EE(mm), EE(mm));
            float thr = __fadd_rn(__fmul_rn(__fmul_rn(EPS2F, fabsf(DD(mm))), fabsf(DD(mm + 1))), SAFMINF);
            if (tst <= thr) { m2 = mm; break; }
          }
        }
        if (m2 < lend) EE(m2) = 0.0f;
        float p = DD(l);
        if (m2 == l) {
          DD(l) = p; l += 1;
          if (l <= lend) continue;
          break;
        }
        if (m2 == l + 1) {
          float rt1, rt2, cc, ss;
          slaev2f(DD(l), EE(l), DD(l + 1), rt1, rt2, cc, ss);
          for (int i = 0; i < 3; ++i) {
            float tz = ZZ(i, l + 1);
            ZZ(i, l + 1) = __fsub_rn(__fmul_rn(cc, tz), __fmul_rn(ss, ZZ(i, l)));
            ZZ(i, l)     = __fadd_rn(__fmul_rn(ss, tz), __fmul_rn(cc, ZZ(i, l)));
          }
          DD(l) = rt1; DD(l + 1) = rt2; EE(l) = 0.0f;
          l += 2;
          if (l <= lend) continue;
          break;
        }
        if (jtot == nmaxit) break;
        jtot++;
        float g = __fdiv_rn(__fsub_rn(DD(l + 1), p), __fmul_rn(2.0f, EE(l)));
        float r = slapy2f(g, 1.0f);
        g = __fadd_rn(__fsub_rn(DD(m2), p), __fdiv_rn(EE(l), __fadd_rn(g, fsignf(r, g))));
        float s = 1.0f, c = 1.0f;
        p = 0.0f;
        for (int i = m2 - 1; i >= l; --i) {
          float f = __fmul_rn(s, EE(i));
          float b = __fmul_rn(c, EE(i));
          slartgf(g, f, c, s, r);
          if (i != m2 - 1) EE(i + 1) = r;
          g = __fsub_rn(DD(i + 1), p);
          r = __fadd_rn(__fmul_rn(__fsub_rn(DD(i), g), s), __fmul_rn(__fmul_rn(2.0f, c), b));
          p = __fmul_rn(s, r);
          DD(i + 1) = __fadd_rn(g, p);
          g = __fsub_rn(__fmul_rn(c, r), b);
          CW(i - l) = c; SW(i - l) = -s;
        }
        int mmc = m2 - l + 1;
        for (int j = mmc - 2; j >= 0; --j) {
          float cj = CW(j), sj = SW(j);
          for (int i = 0; i < 3; ++i) {
            float tz = ZZ(i, l + j + 1);
            ZZ(i, l + j + 1) = __fsub_rn(__fmul_rn(cj, tz), __fmul_rn(sj, ZZ(i, l + j)));
            ZZ(i, l + j)     = __fadd_rn(__fmul_rn(sj, tz), __fmul_rn(cj, ZZ(i, l + j)));
          }
        }
        DD(l) = __fsub_rn(DD(l), p);
        EE(l) = g;
      }
    } else {
      for (int it = 0; it < 120; ++it) {
        int m2 = lend;
        if (l != lend) {
          for (int mm = l; mm >= lend + 1; --mm) {
            float tst = __fmul_rn(EE(mm - 1), EE(mm - 1));
            float thr = __fadd_rn(__fmul_rn(__fmul_rn(EPS2F, fabsf(DD(mm))), fabsf(DD(mm - 1))), SAFMINF);
            if (tst <= thr) { m2 = mm; break; }
          }
        }
        if (m2 > lend) EE(m2 - 1) = 0.0f;
        float p = DD(l);
        if (m2 == l) {
          DD(l) = p; l -= 1;
          if (l >= lend) continue;
          break;
        }
        if (m2 == l - 1) {
          float rt1, rt2, cc, ss;
          slaev2f(DD(l - 1), EE(l - 1), DD(l), rt1, rt2, cc, ss);
          for (int i = 0; i < 3; ++i) {
            float tz = ZZ(i, l);
            ZZ(i, l)     = __fsub_rn(__fmul_rn(cc, tz), __fmul_rn(ss, ZZ(i, l - 1)));
            ZZ(i, l - 1) = __fadd_rn(__fmul_rn(ss, tz), __fmul_rn(cc, ZZ(i, l - 1)));
          }
          DD(l - 1) = rt1; DD(l) = rt2; EE(l - 1) = 0.0f;
          l -= 2;
          if (l >= lend) continue;
          break;
        }
        if (jtot == nmaxit) break;
        jtot++;
        float g = __fdiv_rn(__fsub_rn(DD(l - 1), p), __fmul_rn(2.0f, EE(l - 1)));
        float r = slapy2f(g, 1.0f);
        g = __fadd_rn(__fsub_rn(DD(m2), p), __fdiv_rn(EE(l - 1), __fadd_rn(g, fsignf(r, g))));
        float s = 1.0f, c = 1.0f;
        p = 0.0f;
        for (int i = m2; i <= l - 1; ++i) {
          float f = __fmul_rn(s, EE(i));
          float b = __fmul_rn(c, EE(i));
          slartgf(g, f, c, s, r);
          if (i != m2) EE(i - 1) = r;
          g = __fsub_rn(DD(i), p);
          r = __fadd_rn(__fmul_rn(__fsub_rn(DD(i + 1), g), s), __fmul_rn(__fmul_rn(2.0f, c), b));
          p = __fmul_rn(s, r);
          DD(i) = __fadd_rn(g, p);
          g = __fsub_rn(__fmul_rn(c, r), b);
          CW(i - m2) = c; SW(i - m2) = s;
        }
        int mmc = l - m2 + 1;
        for (int j = 0; j <= mmc - 2; ++j) {
          float cj = CW(j), sj = SW(j);
          for (int i = 0; i < 3; ++i) {
            float tz = ZZ(i, m2 + j + 1);
            ZZ(i, m2 + j + 1) = __fsub_rn(__fmul_rn(cj, tz), __fmul_rn(sj, ZZ(i, m2 + j)));
            ZZ(i, m2 + j)     = __fadd_rn(__fmul_rn(sj, tz), __fmul_rn(cj, ZZ(i, m2 + j)));
          }
        }
        DD(l) = __fsub_rn(DD(l), p);
        EE(l - 1) = g;
      }
    }
    if (jtot >= nmaxit) break;
  }
  for (int ii = 1; ii < 3; ++ii) {
    int i = ii - 1, k = i;
    float p = DD(i);
    for (int j = ii; j < 3; ++j) {
      if (DD(j) < p) { k = j; p = DD(j); }
    }
    if (k != i) {
      DD(k) = DD(i); DD(i) = p;
      for (int r = 0; r < 3; ++r) { float t = ZZ(r, i); ZZ(r, i) = ZZ(r, k); ZZ(r, k) = t; }
    }
  }
}

// Largest f32 bit pattern u >= 0 with sqrt_rn(max(u,1e-12)) <= T.
__device__ __forceinline__ uint32_t d2_ubound(float T) {
  float t2 = __fmul_rn(T, T);
  uint32_t u = __float_as_uint(fmaxf(t2, 0.0f));
  for (int i = 0; i < 64 && u > 0; ++i) {
    if (__fsqrt_rn(fmaxf(__uint_as_float(u), 1e-12f)) <= T) break;
    --u;
  }
  for (int i = 0; i < 64; ++i) {
    if (!(__fsqrt_rn(fmaxf(__uint_as_float(u + 1), 1e-12f)) <= T)) break;
    ++u;
  }
  return u;
}

// monotone cell coordinate (same function in hist/scatter/K1 bounds)
__device__ __forceinline__ int cellf(float x) {
  int c = (int)floorf(__fmul_rn(__fsub_rn(x, GLO), GINV));
  return c < 0 ? 0 : (c > (G - 1) ? (G - 1) : c);
}

// ================= grid build kernels =================

__global__ __launch_bounds__(256)
void hist_kernel(const float* __restrict__ verts, uint32_t* __restrict__ cnt) {
  int i = blockIdx.x * 256 + threadIdx.x;            // 0..16383
  const float* p = verts + (size_t)i * 3;
  uint32_t c = (uint32_t)(i >> 13) * (uint32_t)NCELL +
               (((uint32_t)cellf(p[2]) * G + (uint32_t)cellf(p[1])) * G + (uint32_t)cellf(p[0]));
  atomicAdd(&cnt[c], 1u);
}

// single-block fused scan: exclusive-scan TOTC counts -> start[]; zero cursor
// (cursor aliases cnt -- all reads precede writes per-thread).
__global__ __launch_bounds__(1024)
void scan_kernel(uint32_t* __restrict__ cnt, uint32_t* __restrict__ start) {
  __shared__ uint32_t sh[1024];
  int t = threadIdx.x;
  uint32_t v[SCITEMS];
  uint32_t s = 0;
#pragma unroll
  for (int k = 0; k < SCITEMS; ++k) { v[k] = cnt[t * SCITEMS + k]; s += v[k]; }
  sh[t] = s;
  __syncthreads();
  for (int off = 1; off < 1024; off <<= 1) {
    uint32_t u = (t >= off) ? sh[t - off] : 0u;
    __syncthreads();
    sh[t] += u;
    __syncthreads();
  }
  uint32_t run = sh[t] - s;                          // exclusive base
#pragma unroll
  for (int k = 0; k < SCITEMS; ++k) { start[t * SCITEMS + k] = run; run += v[k]; cnt[t * SCITEMS + k] = 0u; }
  if (t == 1023) start[TOTC] = run;                  // grand total (=16384)
}

__global__ __launch_bounds__(256)
void scatter_kernel(const float* __restrict__ verts, const uint32_t* __restrict__ start,
                    uint32_t* __restrict__ cursor, float4* __restrict__ spts) {
  int i = blockIdx.x * 256 + threadIdx.x;
  const float* p = verts + (size_t)i * 3;
  float px = p[0], py = p[1], pz = p[2];
  uint32_t c = (uint32_t)(i >> 13) * (uint32_t)NCELL +
               (((uint32_t)cellf(pz) * G + (uint32_t)cellf(py)) * G + (uint32_t)cellf(px));
  uint32_t slot = start[c] + atomicAdd(&cursor[c], 1u);
  float4 v;
  v.x = px; v.y = py; v.z = pz;
  v.w = __uint_as_float((uint32_t)(i & (NPTS - 1)));
  spts[slot] = v;
}

// ================= K1: exact KNN selection, grid-binned =================
// Exactness (grid-constant independent): predicate D2<=U, cell superset of
// T-ball (monotone cellf), survivors = ALL points with D2<=U -> top-32
// identical for any qualifying T. Fallback = round-14-verified full scan.

__global__ __launch_bounds__(BTHR)
void knn_select_kernel(const float* __restrict__ verts,
                       const uint32_t* __restrict__ cellstart,
                       const float4* __restrict__ spts,
                       uint16_t* __restrict__ nbr) {
  __shared__ uint64_t SURV[WAVES * CAP];   // 32 KB survivor (d2,idx) keys

  const int tid  = threadIdx.x;
  const int w    = tid >> 6;
  const int lane = tid & 63;
  const int query = blockIdx.x * WAVES + w;
  const int b  = query >> 13;
  const int qi = query & (NPTS - 1);
  const float* vb = verts + (size_t)b * NPTS * 3;

  const float qx = vb[3 * qi + 0], qy = vb[3 * qi + 1], qz = vb[3 * qi + 2];

  // ---- Phase A: sample first 256, T = 6th smallest clamped dist ----
  float sd[4];
#pragma unroll
  for (int s = 0; s < 4; ++s) {
    int j = s * 64 + lane;
    float dxx = __fsub_rn(vb[3 * j + 0], qx);
    float dyy = __fsub_rn(vb[3 * j + 1], qy);
    float dzz = __fsub_rn(vb[3 * j + 2], qz);
    float d2 = __fadd_rn(__fadd_rn(__fmul_rn(dxx, dxx), __fmul_rn(dyy, dyy)), __fmul_rn(dzz, dzz));
    sd[s] = __fsqrt_rn(fmaxf(d2, 1e-12f));
  }
  {
    float lo, hi;
    lo = fminf(sd[0], sd[1]); hi = fmaxf(sd[0], sd[1]); sd[0] = lo; sd[1] = hi;
    lo = fminf(sd[2], sd[3]); hi = fmaxf(sd[2], sd[3]); sd[2] = lo; sd[3] = hi;
    lo = fminf(sd[0], sd[2]); hi = fmaxf(sd[0], sd[2]); sd[0] = lo; sd[2] = hi;
    lo = fminf(sd[1], sd[3]); hi = fmaxf(sd[1], sd[3]); sd[1] = lo; sd[3] = hi;
    lo = fminf(sd[1], sd[2]); hi = fmaxf(sd[1], sd[2]); sd[1] = lo; sd[2] = hi;
  }
  const float INF = __builtin_inff();
  float T = 0.0f;
  for (int r = 0; r < 6; ++r) {
    float g = sd[0];
    for (int o = 32; o; o >>= 1) g = fminf(g, __shfl_xor(g, o));
    bool win = (sd[0] == g) && (g < INF);
    sd[0] = win ? sd[1] : sd[0];
    sd[1] = win ? sd[2] : sd[1];
    sd[2] = win ? sd[3] : sd[2];
    sd[3] = win ? INF   : sd[3];
    if (g < INF) T = g;
  }
  const float Tinit = T;

  // ---- Phase B-grid: binned d2-filtered scan with bounded retry ----
  const uint64_t lmask_lt = (lane == 0) ? 0ull : (~0ull >> (64 - lane));
  uint32_t U = d2_ubound(T);
  const uint32_t cbase = (uint32_t)b * (uint32_t)NCELL;
  int cnt = 0;
  bool grid_ok = false;
  for (int attempt = 0; attempt < 4; ++attempt) {
    float Tq = __fmul_rn(T, 1.00001f);
    int cx0 = cellf(__fsub_rn(qx, Tq)), cx1 = cellf(__fadd_rn(qx, Tq));
    int cy0 = cellf(__fsub_rn(qy, Tq)), cy1 = cellf(__fadd_rn(qy, Tq));
    int cz0 = cellf(__fsub_rn(qz, Tq)), cz1 = cellf(__fadd_rn(qz, Tq));
    int ny = cy1 - cy0 + 1;
    int npairs = ny * (cz1 - cz0 + 1);
    if (npairs > 64) break;                          // -> full-scan fallback
    // parallel prefetch of row bounds (lane r owns row r)
    uint32_t sbegv = 0u, sendv = 0u;
    if (lane < npairs) {
      int rz = lane / ny, ry = lane - rz * ny;
      uint32_t row = cbase + ((uint32_t)(cz0 + rz) * G + (uint32_t)(cy0 + ry)) * G;
      sbegv = cellstart[row + (uint32_t)cx0];
      sendv = cellstart[row + (uint32_t)cx1 + 1];
    }
    cnt = 0;
    for (int r = 0; r < npairs; ++r) {
      uint32_t sbeg = (uint32_t)__shfl((int)sbegv, r);
      uint32_t send = (uint32_t)__shfl((int)sendv, r);
      for (uint32_t i0 = sbeg; i0 < send; i0 += 64) {
        uint32_t i = i0 + (uint32_t)lane;
        bool inb = (i < send);
        uint32_t ii = inb ? i : sbeg;
        float4 v = spts[ii];
        float dxx = __fsub_rn(v.x, qx);
        float dyy = __fsub_rn(v.y, qy);
        float dzz = __fsub_rn(v.z, qz);
        float d2 = __fadd_rn(__fadd_rn(__fmul_rn(dxx, dxx), __fmul_rn(dyy, dyy)), __fmul_rn(dzz, dzz));
        uint32_t D2 = __float_as_uint(d2);
        bool p = inb && (D2 <= U);
        uint64_t m = __ballot(p);
        if (p) {
          int off = cnt + (int)__popcll(m & lmask_lt);
          if (off < CAP) SURV[w * CAP + off] = ((uint64_t)D2 << 32) | (uint64_t)__float_as_uint(v.w);
        }
        cnt += (int)__popcll(m);
      }
    }
    if (cnt > CAP)      { T = __fmul_rn(T, 0.7f); U = d2_ubound(T); continue; }
    else if (cnt < KNN) { T = __fmul_rn(T, 1.8f); U = d2_ubound(T); continue; }
    grid_ok = true;
    break;
  }

  // ---- Phase B-full fallback: round-14-verified full ballot-compact scan ----
  bool fast_ok = grid_ok;
  if (!grid_ok) {
    T = Tinit;
    U = d2_ubound(T);
    for (int attempt = 0; attempt < 8; ++attempt) {
      cnt = 0;
#pragma unroll 4
      for (int s = 0; s < NPTS / 64; ++s) {
        int j = s * 64 + lane;
        float dxx = __fsub_rn(vb[3 * j + 0], qx);
        float dyy = __fsub_rn(vb[3 * j + 1], qy);
        float dzz = __fsub_rn(vb[3 * j + 2], qz);
        float d2 = __fadd_rn(__fadd_rn(__fmul_rn(dxx, dxx), __fmul_rn(dyy, dyy)), __fmul_rn(dzz, dzz));
        uint32_t D2 = __float_as_uint(d2);
        bool p = (D2 <= U);
        uint64_t m = __ballot(p);
        if (p) {
          int off = cnt + (int)__popcll(m & lmask_lt);
          if (off < CAP) SURV[w * CAP + off] = ((uint64_t)D2 << 32) | (uint32_t)j;
        }
        cnt += (int)__popcll(m);
      }
      if (cnt > CAP)      { T = __fmul_rn(T, 0.7f); U = d2_ubound(T); continue; }
      else if (cnt < KNN) { T = __fmul_rn(T, 1.8f); U = d2_ubound(T); continue; }
      fast_ok = true;
      break;
    }
  }

  // ---- Phase C: exact sorted top-32 by (dist,idx); collect per-lane ----
  uint32_t myidx = 0xFFFFFFFFu;
  if (fast_ok) {
    const int n = cnt;
    uint64_t kr[8];
#pragma unroll
    for (int t = 0; t < 8; ++t) {
      int idx = lane + (t << 6);
      if (idx < n) {
        uint64_t v = SURV[w * CAP + idx];
        float dist = __fsqrt_rn(fmaxf(__uint_as_float((uint32_t)(v >> 32)), 1e-12f));
        kr[t] = ((uint64_t)__float_as_uint(dist) << 32) | (uint32_t)v;
      } else {
        kr[t] = ~0ull;
      }
    }
    uint64_t last = 0;
    for (int r = 0; r < KNN; ++r) {
      uint64_t lmin = ~0ull;
#pragma unroll
      for (int t = 0; t < 8; ++t) {
        if ((t << 6) < n) {                          // wave-uniform slot guard
          uint64_t v = kr[t];
          if (v > last && v < lmin) lmin = v;
        }
      }
      uint64_t g = lmin;
      for (int o = 32; o; o >>= 1) {
        uint64_t t2 = __shfl_xor((unsigned long long)g, o);
        if (t2 < g) g = t2;
      }
      if (lane == r) myidx = (uint32_t)g;
      last = g;
    }
  } else {
    // exact exhaustive walk over global verts (never taken in practice)
    uint64_t last = 0;
    for (int r = 0; r < KNN; ++r) {
      uint64_t lmin = ~0ull;
      for (int s = 0; s < NPTS / 64; ++s) {
        int j = s * 64 + lane;
        float dxx = __fsub_rn(vb[3 * j + 0], qx);
        float dyy = __fsub_rn(vb[3 * j + 1], qy);
        float dzz = __fsub_rn(vb[3 * j + 2], qz);
        float d2 = __fadd_rn(__fadd_rn(__fmul_rn(dxx, dxx), __fmul_rn(dyy, dyy)), __fmul_rn(dzz, dzz));
        uint64_t key = ((uint64_t)__float_as_uint(__fsqrt_rn(fmaxf(d2, 1e-12f))) << 32) | (uint32_t)j;
        if (key > last && key < lmin) lmin = key;
      }
      uint64_t g = lmin;
      for (int o = 32; o; o >>= 1) {
        uint64_t t2 = __shfl_xor((unsigned long long)g, o);
        if (t2 < g) g = t2;
      }
      if (lane == r) myidx = (uint32_t)g;
      last = g;
    }
  }

  if (lane < KNN) nbr[(size_t)query * KNN + lane] = (uint16_t)myidx;
}

// ================= K2: downstream (round-5-verified numerics; u16 nbr) =================

__global__ __launch_bounds__(K2BLK)
void shot_lrf_kernel(const float* __restrict__ verts,
                     const uint16_t* __restrict__ nbr,
                     float* __restrict__ out) {
  __shared__ float EW[18 * K2BLK];

  const int tid = threadIdx.x;
  const int query = blockIdx.x * K2BLK + tid;
  const int b  = query >> 13;
  const int qi = query & (NPTS - 1);
  const float* vb = verts + (size_t)b * NPTS * 3;

  const float qx = vb[3 * qi + 0], qy = vb[3 * qi + 1], qz = vb[3 * qi + 2];

  uint32_t idxs[KNN];
#pragma unroll
  for (int k = 0; k < KNN; ++k)
    idxs[k] = (uint32_t)nbr[(size_t)query * KNN + k] & (NPTS - 1);

  float radii;
  {
    int i31 = (int)idxs[KNN - 1];
    float dxx = __fsub_rn(vb[3 * i31 + 0], qx);
    float dyy = __fsub_rn(vb[3 * i31 + 1], qy);
    float dzz = __fsub_rn(vb[3 * i31 + 2], qz);
    float d2 = __fadd_rn(__fadd_rn(__fmul_rn(dxx, dxx), __fmul_rn(dyy, dyy)), __fmul_rn(dzz, dzz));
    radii = __fsqrt_rn(fmaxf(d2, 1e-12f));
  }

  float rr[8];
#pragma unroll
  for (int i = 0; i < 8; ++i) rr[i] = 0.0f;
  float l00[4], l10[4], l20[4], l11[4], l21[4], l22[4];
#pragma unroll
  for (int L = 0; L < 4; ++L) { l00[L]=0.0f; l10[L]=0.0f; l20[L]=0.0f; l11[L]=0.0f; l21[L]=0.0f; l22[L]=0.0f; }
#pragma unroll
  for (int c = 0; c < 8; ++c) {
#pragma unroll
    for (int L = 0; L < 4; ++L) {
      int k2 = 4 * c + L;
      int idx = (int)idxs[k2];
      float dxx = __fsub_rn(vb[3 * idx + 0], qx);
      float dyy = __fsub_rn(vb[3 * idx + 1], qy);
      float dzz = __fsub_rn(vb[3 * idx + 2], qz);
      float d2 = __fadd_rn(__fadd_rn(__fmul_rn(dxx, dxx), __fmul_rn(dyy, dyy)), __fmul_rn(dzz, dzz));
      float dist = __fsqrt_rn(fmaxf(d2, 1e-12f));
      float wgt = __fsub_rn(radii, dist);
      rr[k2 & 7] = __fadd_rn(rr[k2 & 7], wgt);
      float wx = __fmul_rn(wgt, dxx), wy = __fmul_rn(wgt, dyy), wz = __fmul_rn(wgt, dzz);
      l00[L] = __fadd_rn(l00[L], __fmul_rn(wx, dxx));
      l10[L] = __fadd_rn(l10[L], __fmul_rn(wy, dxx));
      l20[L] = __fadd_rn(l20[L], __fmul_rn(wz, dxx));
      l11[L] = __fadd_rn(l11[L], __fmul_rn(wy, dyy));
      l21[L] = __fadd_rn(l21[L], __fmul_rn(wz, dyy));
      l22[L] = __fadd_rn(l22[L], __fmul_rn(wz, dzz));
    }
  }
  float c00 = __fadd_rn(__fadd_rn(l00[0], l00[1]), __fadd_rn(l00[2], l00[3]));
  float c10 = __fadd_rn(__fadd_rn(l10[0], l10[1]), __fadd_rn(l10[2], l10[3]));
  float c20 = __fadd_rn(__fadd_rn(l20[0], l20[1]), __fadd_rn(l20[2], l20[3]));
  float c11 = __fadd_rn(__fadd_rn(l11[0], l11[1]), __fadd_rn(l11[2], l11[3]));
  float c21 = __fadd_rn(__fadd_rn(l21[0], l21[1]), __fadd_rn(l21[2], l21[3]));
  float c22 = __fadd_rn(__fadd_rn(l22[0], l22[1]), __fadd_rn(l22[2], l22[3]));
  float sumw = __fadd_rn(
      __fadd_rn(__fadd_rn(rr[0], rr[1]), __fadd_rn(rr[2], rr[3])),
      __fadd_rn(__fadd_rn(rr[4], rr[5]), __fadd_rn(rr[6], rr[7])));

  float a11 = __fdiv_rn(c00, sumw);
  float a21 = __fdiv_rn(c10, sumw);
  float a31 = __fdiv_rn(c20, sumw);
  float a22 = __fdiv_rn(c11, sumw);
  float a32 = __fdiv_rn(c21, sumw);
  float a33 = __fdiv_rn(c22, sumw);

  float* base = &EW[tid];
  float taui, v2;
  {
    float alpha = a21;
    float xnorm = fabsf(a31);
    float beta;
    if (xnorm == 0.0f) {
      taui = 0.0f; v2 = 0.0f; beta = alpha;
      DD(0) = a11; DD(1) = a22; DD(2) = a33;
      EE(0) = beta; EE(1) = a32;
    } else {
      beta = -fsignf(slapy2f(alpha, xnorm), alpha);
      taui = __fdiv_rn(__fsub_rn(beta, alpha), beta);
      float inv = __fdiv_rn(1.0f, __fsub_rn(alpha, beta));
      v2 = __fmul_rn(a31, inv);
      float y1 = __fmul_rn(taui, a22);
      float y2 = __fmul_rn(taui, a32);
      float temp2 = __fmul_rn(a32, v2);
      y1 = __fadd_rn(y1, __fmul_rn(taui, temp2));
      y2 = __fadd_rn(y2, __fmul_rn(__fmul_rn(taui, v2), a33));
      float dot = __fadd_rn(y1, __fmul_rn(y2, v2));
      float aw = __fmul_rn(__fmul_rn(-0.5f, taui), dot);
      float w1 = __fadd_rn(y1, aw);
      float w2 = __fadd_rn(y2, __fmul_rn(aw, v2));
      float a22p = __fadd_rn(__fadd_rn(a22, __fmul_rn(1.0f, -w1)), __fmul_rn(w1, -1.0f));
      float a32p = __fadd_rn(__fadd_rn(a32, __fmul_rn(v2, -w1)), __fmul_rn(w2, -1.0f));
      float a33p = __fadd_rn(__fadd_rn(a33, __fmul_rn(v2, -w2)), __fmul_rn(w2, -v2));
      DD(0) = a11; DD(1) = a22p; DD(2) = a33p;
      EE(0) = beta; EE(1) = a32p;
    }
  }

  for (int i = 0; i < 3; ++i)
    for (int j = 0; j < 3; ++j)
      ZZ(i, j) = (i == j) ? 1.0f : 0.0f;

  steqr3f(base);

  if (taui != 0.0f) {
    for (int j = 0; j < 3; ++j) {
      float wj = __fadd_rn(ZZ(1, j), __fmul_rn(ZZ(2, j), v2));
      float t = __fmul_rn(-taui, wj);
      ZZ(1, j) = __fadd_rn(ZZ(1, j), t);
      ZZ(2, j) = __fadd_rn(ZZ(2, j), __fmul_rn(v2, t));
    }
  }

  float X0 = ZZ(0, 2), X1 = ZZ(1, 2), X2 = ZZ(2, 2);
  float Z0 = ZZ(0, 0), Z1 = ZZ(1, 0), Z2 = ZZ(2, 0);

  int npx = 0, npz = 0;
#pragma unroll
  for (int k2 = 0; k2 < KNN; ++k2) {
    int idx = (int)idxs[k2];
    float dxx = __fsub_rn(vb[3 * idx + 0], qx);
    float dyy = __fsub_rn(vb[3 * idx + 1], qy);
    float dzz = __fsub_rn(vb[3 * idx + 2], qz);
    float px = __fadd_rn(__fadd_rn(__fmul_rn(dxx, X0), __fmul_rn(dyy, X1)), __fmul_rn(dzz, X2));
    float pz = __fadd_rn(__fadd_rn(__fmul_rn(dxx, Z0), __fmul_rn(dyy, Z1)), __fmul_rn(dzz, Z2));
    if (px >= 0.0f) npx++;
    if (pz >= 0.0f) npz++;
  }
  if (2 * npx < KNN) { X0 = -X0; X1 = -X1; X2 = -X2; }
  if (2 * npz < KNN) { Z0 = -Z0; Z1 = -Z1; Z2 = -Z2; }

  float Y0 = __fsub_rn(__fmul_rn(Z1, X2), __fmul_rn(Z2, X1));
  float Y1 = __fsub_rn(__fmul_rn(Z2, X0), __fmul_rn(Z0, X2));
  float Y2 = __fsub_rn(__fmul_rn(Z0, X1), __fmul_rn(Z1, X0));

  float* o = out + (size_t)query * 9;
  o[0] = X0; o[1] = X1; o[2] = X2;
  o[3] = Y0; o[4] = Y1; o[5] = Y2;
  o[6] = Z0; o[7] = Z1; o[8] = Z2;
}

#undef ZZ
#undef DD
#undef EE
#undef CW
#undef SW

extern "C" void kernel_launch(void* const* d_in, const int* in_sizes, int n_in,
                              void* d_out, int out_size, void* d_ws, size_t ws_size,
                              hipStream_t stream) {
  (void)n_in; (void)out_size; (void)ws_size;
  const float* verts = (const float*)d_in[0];
  float* out = (float*)d_out;
  int total = in_sizes[0] / 3;               // 16384 queries

  // ws layout (~1.47 MiB; 2 MiB proven available)
  char* ws = (char*)d_ws;
  uint16_t* nbr    = (uint16_t*)(ws);                               // 1,048,576 B
  uint32_t* cstart = (uint32_t*)(ws + 1048576);                     // (TOTC+1)*4 = 110,596 B, pad 110,720
  uint32_t* ccnt   = (uint32_t*)(ws + 1048576 + 110720);            // TOTC*4 = 110,592 B (doubles as cursor)
  float4*   spts   = (float4*)  (ws + 1048576 + 110720 + 110592);   // 262,144 B (16B aligned)

  hipMemsetAsync(ccnt, 0, (size_t)TOTC * 4, stream);
  hist_kernel   <<<total / 256, 256, 0, stream>>>(verts, ccnt);
  scan_kernel   <<<1, 1024, 0, stream>>>(ccnt, cstart);             // also zeroes cursor
  scatter_kernel<<<total / 256, 256, 0, stream>>>(verts, cstart, ccnt, spts);
  knn_select_kernel<<<total / WAVES, BTHR, 0, stream>>>(verts, cstart, spts, nbr);
  shot_lrf_kernel<<<total / K2BLK, K2BLK, 0, stream>>>(verts, nbr, out);
}

// Round 19
// 172.573 us; speedup vs baseline: 1.1507x; 1.1507x over previous
//
#include <hip/hip_runtime.h>
#include <stdint.h>

#define NPTS 8192
#define KNN  32
#define WAVES 8
#define BTHR (WAVES*64)
#define CAP  512
#define K2BLK 64

// grid (G=16: cell 0.75) -- bracketed optimum: G=32 and G=24 both measured worse
#define G     16
#define NCELL 4096           // per batch
#define TOTC  8192           // both batches
#define GLO   (-6.0f)
#define GINV  (1.3333334f)   // 1/0.75

// ---------------- f32 LAPACK constants (SLAMCH) ----------------
#define EPSF    5.9604645e-08f
#define EPS2F   3.5527137e-15f
#define SAFMINF 1.17549435e-38f
#define SAFMAXF 8.5070592e+37f
#define RTMINF  1.0842022e-19f
#define RTMAXF  9.2233720e+18f

__device__ __forceinline__ float fsignf(float a, float b) {
  return __builtin_copysignf(fabsf(a), b);
}

__device__ __forceinline__ float slapy2f(float x, float y) {
  float xa = fabsf(x), ya = fabsf(y);
  float w = fmaxf(xa, ya), z = fminf(xa, ya);
  if (z == 0.0f) return w;
  float t = __fdiv_rn(z, w);
  return __fmul_rn(w, __fsqrt_rn(__fadd_rn(1.0f, __fmul_rn(t, t))));
}

// LAPACK >= 3.10 slartg
__device__ __forceinline__ void slartgf(float f, float g, float& c, float& s, float& r) {
  if (g == 0.0f)      { c = 1.0f; s = 0.0f; r = f; }
  else if (f == 0.0f) { c = 0.0f; s = __builtin_copysignf(1.0f, g); r = fabsf(g); }
  else {
    float f1 = fabsf(f), g1 = fabsf(g);
    if (f1 > RTMINF && f1 < RTMAXF && g1 > RTMINF && g1 < RTMAXF) {
      float d = __fsqrt_rn(__fadd_rn(__fmul_rn(f, f), __fmul_rn(g, g)));
      c = __fdiv_rn(f1, d);
      r = __builtin_copysignf(d, f);
      s = __fdiv_rn(g, r);
    } else {
      float u  = fminf(SAFMAXF, fmaxf(SAFMINF, fmaxf(f1, g1)));
      float fs = __fdiv_rn(f, u), gs = __fdiv_rn(g, u);
      float d  = __fsqrt_rn(__fadd_rn(__fmul_rn(fs, fs), __fmul_rn(gs, gs)));
      c = __fdiv_rn(fabsf(fs), d);
      r = __builtin_copysignf(d, f);
      s = __fdiv_rn(gs, r);
      r = __fmul_rn(r, u);
    }
  }
}

__device__ void slaev2f(float a, float b, float c,
                        float& rt1, float& rt2, float& cs1, float& sn1) {
  float sm = __fadd_rn(a, c), df = __fsub_rn(a, c);
  float adf = fabsf(df), tb = __fadd_rn(b, b), ab = fabsf(tb);
  float acmx, acmn;
  if (fabsf(a) > fabsf(c)) { acmx = a; acmn = c; } else { acmx = c; acmn = a; }
  float rt;
  if (adf > ab) {
    float t = __fdiv_rn(ab, adf);
    rt = __fmul_rn(adf, __fsqrt_rn(__fadd_rn(1.0f, __fmul_rn(t, t))));
  } else if (adf < ab) {
    float t = __fdiv_rn(adf, ab);
    rt = __fmul_rn(ab, __fsqrt_rn(__fadd_rn(1.0f, __fmul_rn(t, t))));
  } else {
    rt = __fmul_rn(ab, __fsqrt_rn(2.0f));
  }
  int sgn1;
  if (sm < 0.0f) {
    rt1 = __fmul_rn(0.5f, __fsub_rn(sm, rt)); sgn1 = -1;
    rt2 = __fsub_rn(__fmul_rn(__fdiv_rn(acmx, rt1), acmn), __fmul_rn(__fdiv_rn(b, rt1), b));
  } else if (sm > 0.0f) {
    rt1 = __fmul_rn(0.5f, __fadd_rn(sm, rt)); sgn1 = 1;
    rt2 = __fsub_rn(__fmul_rn(__fdiv_rn(acmx, rt1), acmn), __fmul_rn(__fdiv_rn(b, rt1), b));
  } else {
    rt1 = __fmul_rn(0.5f, rt); rt2 = -rt1; sgn1 = 1;
  }
  float cs; int sgn2;
  if (df >= 0.0f) { cs = __fadd_rn(df, rt); sgn2 = 1; }
  else            { cs = __fsub_rn(df, rt); sgn2 = -1; }
  float acs = fabsf(cs);
  if (acs > ab) {
    float ct = __fdiv_rn(-tb, cs);
    sn1 = __fdiv_rn(1.0f, __fsqrt_rn(__fadd_rn(1.0f, __fmul_rn(ct, ct))));
    cs1 = __fmul_rn(ct, sn1);
  } else {
    if (ab == 0.0f) { cs1 = 1.0f; sn1 = 0.0f; }
    else {
      float tn = __fdiv_rn(-cs, tb);
      cs1 = __fdiv_rn(1.0f, __fsqrt_rn(__fadd_rn(1.0f, __fmul_rn(tn, tn))));
      sn1 = __fmul_rn(tn, cs1);
    }
  }
  if (sgn1 == sgn2) { float tn = cs1; cs1 = -sn1; sn1 = tn; }
}

// Per-lane eigensolver state in LDS, strided by K2BLK (round-5-verified layout).
#define ZZ(i,j) base[((i)*3+(j))*K2BLK]
#define DD(i)   base[(9+(i))*K2BLK]
#define EE(i)   base[(12+(i))*K2BLK]
#define CW(i)   base[(14+(i))*K2BLK]
#define SW(i)   base[(16+(i))*K2BLK]

__device__ void steqr3f(float* base) {
  const int nmaxit = 90;
  int jtot = 0;
  int l1 = 0;
  for (int outer = 0; outer < 6; ++outer) {
    if (l1 > 2) break;
    if (l1 > 0) EE(l1 - 1) = 0.0f;
    int m = 2;
    for (int mm = l1; mm <= 1; ++mm) {
      float tst = fabsf(EE(mm));
      if (tst == 0.0f) { m = mm; break; }
      float thr = __fmul_rn(__fmul_rn(__fsqrt_rn(fabsf(DD(mm))), __fsqrt_rn(fabsf(DD(mm + 1)))), EPSF);
      if (tst <= thr) { EE(mm) = 0.0f; m = mm; break; }
    }
    int l = l1;
    int lend = m;
    l1 = m + 1;
    if (lend == l) continue;
    if (fabsf(DD(lend)) < fabsf(DD(l))) { int t = l; l = lend; lend = t; }
    if (lend > l) {
      for (int it = 0; it < 120; ++it) {
        int m2 = lend;
        if (l != lend) {
          for (int mm = l; mm <= lend - 1; ++mm) {
            float tst = __fmul_rn(EE(mm), EE(mm));
            float thr = __fadd_rn(__fmul_rn(__fmul_rn(EPS2F, fabsf(DD(mm))), fabsf(DD(mm + 1))), SAFMINF);
            if (tst <= thr) { m2 = mm; break; }
          }
        }
        if (m2 < lend) EE(m2) = 0.0f;
        float p = DD(l);
        if (m2 == l) {
          DD(l) = p; l += 1;
          if (l <= lend) continue;
          break;
        }
        if (m2 == l + 1) {
          float rt1, rt2, cc, ss;
          slaev2f(DD(l), EE(l), DD(l + 1), rt1, rt2, cc, ss);
          for (int i = 0; i < 3; ++i) {
            float tz = ZZ(i, l + 1);
            ZZ(i, l + 1) = __fsub_rn(__fmul_rn(cc, tz), __fmul_rn(ss, ZZ(i, l)));
            ZZ(i, l)     = __fadd_rn(__fmul_rn(ss, tz), __fmul_rn(cc, ZZ(i, l)));
          }
          DD(l) = rt1; DD(l + 1) = rt2; EE(l) = 0.0f;
          l += 2;
          if (l <= lend) continue;
          break;
        }
        if (jtot == nmaxit) break;
        jtot++;
        float g = __fdiv_rn(__fsub_rn(DD(l + 1), p), __fmul_rn(2.0f, EE(l)));
        float r = slapy2f(g, 1.0f);
        g = __fadd_rn(__fsub_rn(DD(m2), p), __fdiv_rn(EE(l), __fadd_rn(g, fsignf(r, g))));
        float s = 1.0f, c = 1.0f;
        p = 0.0f;
        for (int i = m2 - 1; i >= l; --i) {
          float f = __fmul_rn(s, EE(i));
          float b = __fmul_rn(c, EE(i));
          slartgf(g, f, c, s, r);
          if (i != m2 - 1) EE(i + 1) = r;
          g = __fsub_rn(DD(i + 1), p);
          r = __fadd_rn(__fmul_rn(__fsub_rn(DD(i), g), s), __fmul_rn(__fmul_rn(2.0f, c), b));
          p = __fmul_rn(s, r);
          DD(i + 1) = __fadd_rn(g, p);
          g = __fsub_rn(__fmul_rn(c, r), b);
          CW(i - l) = c; SW(i - l) = -s;
        }
        int mmc = m2 - l + 1;
        for (int j = mmc - 2; j >= 0; --j) {
          float cj = CW(j), sj = SW(j);
          for (int i = 0; i < 3; ++i) {
            float tz = ZZ(i, l + j + 1);
            ZZ(i, l + j + 1) = __fsub_rn(__fmul_rn(cj, tz), __fmul_rn(sj, ZZ(i, l + j)));
            ZZ(i, l + j)     = __fadd_rn(__fmul_rn(sj, tz), __fmul_rn(cj, ZZ(i, l + j)));
          }
        }
        DD(l) = __fsub_rn(DD(l), p);
        EE(l) = g;
      }
    } else {
      for (int it = 0; it < 120; ++it) {
        int m2 = lend;
        if (l != lend) {
          for (int mm = l; mm >= lend + 1; --mm) {
            float tst = __fmul_rn(EE(mm - 1), EE(mm - 1));
            float thr = __fadd_rn(__fmul_rn(__fmul_rn(EPS2F, fabsf(DD(mm))), fabsf(DD(mm - 1))), SAFMINF);
            if (tst <= thr) { m2 = mm; break; }
          }
        }
        if (m2 > lend) EE(m2 - 1) = 0.0f;
        float p = DD(l);
        if (m2 == l) {
          DD(l) = p; l -= 1;
          if (l >= lend) continue;
          break;
        }
        if (m2 == l - 1) {
          float rt1, rt2, cc, ss;
          slaev2f(DD(l - 1), EE(l - 1), DD(l), rt1, rt2, cc, ss);
          for (int i = 0; i < 3; ++i) {
            float tz = ZZ(i, l);
            ZZ(i, l)     = __fsub_rn(__fmul_rn(cc, tz), __fmul_rn(ss, ZZ(i, l - 1)));
            ZZ(i, l - 1) = __fadd_rn(__fmul_rn(ss, tz), __fmul_rn(cc, ZZ(i, l - 1)));
          }
          DD(l - 1) = rt1; DD(l) = rt2; EE(l - 1) = 0.0f;
          l -= 2;
          if (l >= lend) continue;
          break;
        }
        if (jtot == nmaxit) break;
        jtot++;
        float g = __fdiv_rn(__fsub_rn(DD(l - 1), p), __fmul_rn(2.0f, EE(l - 1)));
        float r = slapy2f(g, 1.0f);
        g = __fadd_rn(__fsub_rn(DD(m2), p), __fdiv_rn(EE(l - 1), __fadd_rn(g, fsignf(r, g))));
        float s = 1.0f, c = 1.0f;
        p = 0.0f;
        for (int i = m2; i <= l - 1; ++i) {
          float f = __fmul_rn(s, EE(i));
          float b = __fmul_rn(c, EE(i));
          slartgf(g, f, c, s, r);
          if (i != m2) EE(i - 1) = r;
          g = __fsub_rn(DD(i), p);
          r = __fadd_rn(__fmul_rn(__fsub_rn(DD(i + 1), g), s), __fmul_rn(__fmul_rn(2.0f, c), b));
          p = __fmul_rn(s, r);
          DD(i) = __fadd_rn(g, p);
          g = __fsub_rn(__fmul_rn(c, r), b);
          CW(i - m2) = c; SW(i - m2) = s;
        }
        int mmc = l - m2 + 1;
        for (int j = 0; j <= mmc - 2; ++j) {
          float cj = CW(j), sj = SW(j);
          for (int i = 0; i < 3; ++i) {
            float tz = ZZ(i, m2 + j + 1);
            ZZ(i, m2 + j + 1) = __fsub_rn(__fmul_rn(cj, tz), __fmul_rn(sj, ZZ(i, m2 + j)));
            ZZ(i, m2 + j)     = __fadd_rn(__fmul_rn(sj, tz), __fmul_rn(cj, ZZ(i, m2 + j)));
          }
        }
        DD(l) = __fsub_rn(DD(l), p);
        EE(l - 1) = g;
      }
    }
    if (jtot >= nmaxit) break;
  }
  for (int ii = 1; ii < 3; ++ii) {
    int i = ii - 1, k = i;
    float p = DD(i);
    for (int j = ii; j < 3; ++j) {
      if (DD(j) < p) { k = j; p = DD(j); }
    }
    if (k != i) {
      DD(k) = DD(i); DD(i) = p;
      for (int r = 0; r < 3; ++r) { float t = ZZ(r, i); ZZ(r, i) = ZZ(r, k); ZZ(r, k) = t; }
    }
  }
}

// Largest f32 bit pattern u >= 0 with sqrt_rn(max(u,1e-12)) <= T.
__device__ __forceinline__ uint32_t d2_ubound(float T) {
  float t2 = __fmul_rn(T, T);
  uint32_t u = __float_as_uint(fmaxf(t2, 0.0f));
  for (int i = 0; i < 64 && u > 0; ++i) {
    if (__fsqrt_rn(fmaxf(__uint_as_float(u), 1e-12f)) <= T) break;
    --u;
  }
  for (int i = 0; i < 64; ++i) {
    if (!(__fsqrt_rn(fmaxf(__uint_as_float(u + 1), 1e-12f)) <= T)) break;
    ++u;
  }
  return u;
}

// monotone cell coordinate (same function in hist/scatter/K1 bounds)
__device__ __forceinline__ int cellf(float x) {
  int c = (int)floorf(__fmul_rn(__fsub_rn(x, GLO), GINV));
  return c < 0 ? 0 : (c > (G - 1) ? (G - 1) : c);
}

// ================= grid build kernels =================

__global__ __launch_bounds__(256)
void hist_kernel(const float* __restrict__ verts, uint32_t* __restrict__ cnt) {
  int i = blockIdx.x * 256 + threadIdx.x;            // 0..16383
  const float* p = verts + (size_t)i * 3;
  uint32_t c = (uint32_t)(i >> 13) * (uint32_t)NCELL +
               (((uint32_t)cellf(p[2]) * G + (uint32_t)cellf(p[1])) * G + (uint32_t)cellf(p[0]));
  atomicAdd(&cnt[c], 1u);
}

// single-block fused scan: exclusive-scan 8192 counts -> start[]; zero cursor
// (cursor aliases cnt -- all reads precede writes per-thread).
__global__ __launch_bounds__(1024)
void scan_kernel(uint32_t* __restrict__ cnt, uint32_t* __restrict__ start) {
  __shared__ uint32_t sh[1024];
  int t = threadIdx.x;
  uint32_t v[8];
  uint32_t s = 0;
#pragma unroll
  for (int k = 0; k < 8; ++k) { v[k] = cnt[t * 8 + k]; s += v[k]; }
  sh[t] = s;
  __syncthreads();
  for (int off = 1; off < 1024; off <<= 1) {
    uint32_t u = (t >= off) ? sh[t - off] : 0u;
    __syncthreads();
    sh[t] += u;
    __syncthreads();
  }
  uint32_t run = sh[t] - s;                          // exclusive base
#pragma unroll
  for (int k = 0; k < 8; ++k) { start[t * 8 + k] = run; run += v[k]; cnt[t * 8 + k] = 0u; }
  if (t == 1023) start[TOTC] = run;                  // grand total (=16384)
}

__global__ __launch_bounds__(256)
void scatter_kernel(const float* __restrict__ verts, const uint32_t* __restrict__ start,
                    uint32_t* __restrict__ cursor, float4* __restrict__ spts) {
  int i = blockIdx.x * 256 + threadIdx.x;
  const float* p = verts + (size_t)i * 3;
  float px = p[0], py = p[1], pz = p[2];
  uint32_t c = (uint32_t)(i >> 13) * (uint32_t)NCELL +
               (((uint32_t)cellf(pz) * G + (uint32_t)cellf(py)) * G + (uint32_t)cellf(px));
  uint32_t slot = start[c] + atomicAdd(&cursor[c], 1u);
  float4 v;
  v.x = px; v.y = py; v.z = pz;
  v.w = __uint_as_float((uint32_t)(i & (NPTS - 1)));
  spts[slot] = v;
}

// ================= K1: exact KNN selection, grid-binned =================
// Exactness (grid-constant independent): predicate D2<=U, cell superset of
// T-ball (monotone cellf), survivors = ALL points with D2<=U -> top-32
// identical for any qualifying T. Fallback = round-14-verified full scan.

__global__ __launch_bounds__(BTHR)
void knn_select_kernel(const float* __restrict__ verts,
                       const uint32_t* __restrict__ cellstart,
                       const float4* __restrict__ spts,
                       uint16_t* __restrict__ nbr) {
  __shared__ uint64_t SURV[WAVES * CAP];   // 32 KB survivor (d2,idx) keys

  const int tid  = threadIdx.x;
  const int w    = tid >> 6;
  const int lane = tid & 63;
  const int query = blockIdx.x * WAVES + w;
  const int b  = query >> 13;
  const int qi = query & (NPTS - 1);
  const float* vb = verts + (size_t)b * NPTS * 3;

  const float qx = vb[3 * qi + 0], qy = vb[3 * qi + 1], qz = vb[3 * qi + 2];

  // ---- Phase A: sample first 256, T = 6th smallest clamped dist ----
  float sd[4];
#pragma unroll
  for (int s = 0; s < 4; ++s) {
    int j = s * 64 + lane;
    float dxx = __fsub_rn(vb[3 * j + 0], qx);
    float dyy = __fsub_rn(vb[3 * j + 1], qy);
    float dzz = __fsub_rn(vb[3 * j + 2], qz);
    float d2 = __fadd_rn(__fadd_rn(__fmul_rn(dxx, dxx), __fmul_rn(dyy, dyy)), __fmul_rn(dzz, dzz));
    sd[s] = __fsqrt_rn(fmaxf(d2, 1e-12f));
  }
  {
    float lo, hi;
    lo = fminf(sd[0], sd[1]); hi = fmaxf(sd[0], sd[1]); sd[0] = lo; sd[1] = hi;
    lo = fminf(sd[2], sd[3]); hi = fmaxf(sd[2], sd[3]); sd[2] = lo; sd[3] = hi;
    lo = fminf(sd[0], sd[2]); hi = fmaxf(sd[0], sd[2]); sd[0] = lo; sd[2] = hi;
    lo = fminf(sd[1], sd[3]); hi = fmaxf(sd[1], sd[3]); sd[1] = lo; sd[3] = hi;
    lo = fminf(sd[1], sd[2]); hi = fmaxf(sd[1], sd[2]); sd[1] = lo; sd[2] = hi;
  }
  const float INF = __builtin_inff();
  float T = 0.0f;
  for (int r = 0; r < 6; ++r) {
    float g = sd[0];
    for (int o = 32; o; o >>= 1) g = fminf(g, __shfl_xor(g, o));
    bool win = (sd[0] == g) && (g < INF);
    sd[0] = win ? sd[1] : sd[0];
    sd[1] = win ? sd[2] : sd[1];
    sd[2] = win ? sd[3] : sd[2];
    sd[3] = win ? INF   : sd[3];
    if (g < INF) T = g;
  }
  const float Tinit = T;

  // ---- Phase B-grid: binned d2-filtered scan with bounded retry ----
  const uint64_t lmask_lt = (lane == 0) ? 0ull : (~0ull >> (64 - lane));
  uint32_t U = d2_ubound(T);
  const uint32_t cbase = (uint32_t)b * (uint32_t)NCELL;
  int cnt = 0;
  bool grid_ok = false;
  for (int attempt = 0; attempt < 4; ++attempt) {
    float Tq = __fmul_rn(T, 1.00001f);
    int cx0 = cellf(__fsub_rn(qx, Tq)), cx1 = cellf(__fadd_rn(qx, Tq));
    int cy0 = cellf(__fsub_rn(qy, Tq)), cy1 = cellf(__fadd_rn(qy, Tq));
    int cz0 = cellf(__fsub_rn(qz, Tq)), cz1 = cellf(__fadd_rn(qz, Tq));
    int ny = cy1 - cy0 + 1;
    int npairs = ny * (cz1 - cz0 + 1);
    if (npairs > 64) break;                          // -> full-scan fallback
    // parallel prefetch of row bounds (lane r owns row r)
    uint32_t sbegv = 0u, sendv = 0u;
    if (lane < npairs) {
      int rz = lane / ny, ry = lane - rz * ny;
      uint32_t row = cbase + ((uint32_t)(cz0 + rz) * G + (uint32_t)(cy0 + ry)) * G;
      sbegv = cellstart[row + (uint32_t)cx0];
      sendv = cellstart[row + (uint32_t)cx1 + 1];
    }
    cnt = 0;
    for (int r = 0; r < npairs; ++r) {
      uint32_t sbeg = (uint32_t)__shfl((int)sbegv, r);
      uint32_t send = (uint32_t)__shfl((int)sendv, r);
      for (uint32_t i0 = sbeg; i0 < send; i0 += 64) {
        uint32_t i = i0 + (uint32_t)lane;
        bool inb = (i < send);
        uint32_t ii = inb ? i : sbeg;
        float4 v = spts[ii];
        float dxx = __fsub_rn(v.x, qx);
        float dyy = __fsub_rn(v.y, qy);
        float dzz = __fsub_rn(v.z, qz);
        float d2 = __fadd_rn(__fadd_rn(__fmul_rn(dxx, dxx), __fmul_rn(dyy, dyy)), __fmul_rn(dzz, dzz));
        uint32_t D2 = __float_as_uint(d2);
        bool p = inb && (D2 <= U);
        uint64_t m = __ballot(p);
        if (p) {
          int off = cnt + (int)__popcll(m & lmask_lt);
          if (off < CAP) SURV[w * CAP + off] = ((uint64_t)D2 << 32) | (uint64_t)__float_as_uint(v.w);
        }
        cnt += (int)__popcll(m);
      }
    }
    if (cnt > CAP)      { T = __fmul_rn(T, 0.7f); U = d2_ubound(T); continue; }
    else if (cnt < KNN) { T = __fmul_rn(T, 1.8f); U = d2_ubound(T); continue; }
    grid_ok = true;
    break;
  }

  // ---- Phase B-full fallback: round-14-verified full ballot-compact scan ----
  bool fast_ok = grid_ok;
  if (!grid_ok) {
    T = Tinit;
    U = d2_ubound(T);
    for (int attempt = 0; attempt < 8; ++attempt) {
      cnt = 0;
#pragma unroll 4
      for (int s = 0; s < NPTS / 64; ++s) {
        int j = s * 64 + lane;
        float dxx = __fsub_rn(vb[3 * j + 0], qx);
        float dyy = __fsub_rn(vb[3 * j + 1], qy);
        float dzz = __fsub_rn(vb[3 * j + 2], qz);
        float d2 = __fadd_rn(__fadd_rn(__fmul_rn(dxx, dxx), __fmul_rn(dyy, dyy)), __fmul_rn(dzz, dzz));
        uint32_t D2 = __float_as_uint(d2);
        bool p = (D2 <= U);
        uint64_t m = __ballot(p);
        if (p) {
          int off = cnt + (int)__popcll(m & lmask_lt);
          if (off < CAP) SURV[w * CAP + off] = ((uint64_t)D2 << 32) | (uint32_t)j;
        }
        cnt += (int)__popcll(m);
      }
      if (cnt > CAP)      { T = __fmul_rn(T, 0.7f); U = d2_ubound(T); continue; }
      else if (cnt < KNN) { T = __fmul_rn(T, 1.8f); U = d2_ubound(T); continue; }
      fast_ok = true;
      break;
    }
  }

  // ---- Phase C: exact sorted top-32 by (dist,idx); collect per-lane ----
  uint32_t myidx = 0xFFFFFFFFu;
  if (fast_ok) {
    const int n = cnt;
    uint64_t kr[8];
#pragma unroll
    for (int t = 0; t < 8; ++t) {
      int idx = lane + (t << 6);
      if (idx < n) {
        uint64_t v = SURV[w * CAP + idx];
        float dist = __fsqrt_rn(fmaxf(__uint_as_float((uint32_t)(v >> 32)), 1e-12f));
        kr[t] = ((uint64_t)__float_as_uint(dist) << 32) | (uint32_t)v;
      } else {
        kr[t] = ~0ull;
      }
    }
    uint64_t last = 0;
    for (int r = 0; r < KNN; ++r) {
      uint64_t lmin = ~0ull;
#pragma unroll
      for (int t = 0; t < 8; ++t) {
        if ((t << 6) < n) {                          // wave-uniform slot guard
          uint64_t v = kr[t];
          if (v > last && v < lmin) lmin = v;
        }
      }
      uint64_t g = lmin;
      for (int o = 32; o; o >>= 1) {
        uint64_t t2 = __shfl_xor((unsigned long long)g, o);
        if (t2 < g) g = t2;
      }
      if (lane == r) myidx = (uint32_t)g;
      last = g;
    }
  } else {
    // exact exhaustive walk over global verts (never taken in practice)
    uint64_t last = 0;
    for (int r = 0; r < KNN; ++r) {
      uint64_t lmin = ~0ull;
      for (int s = 0; s < NPTS / 64; ++s) {
        int j = s * 64 + lane;
        float dxx = __fsub_rn(vb[3 * j + 0], qx);
        float dyy = __fsub_rn(vb[3 * j + 1], qy);
        float dzz = __fsub_rn(vb[3 * j + 2], qz);
        float d2 = __fadd_rn(__fadd_rn(__fmul_rn(dxx, dxx), __fmul_rn(dyy, dyy)), __fmul_rn(dzz, dzz));
        uint64_t key = ((uint64_t)__float_as_uint(__fsqrt_rn(fmaxf(d2, 1e-12f))) << 32) | (uint32_t)j;
        if (key > last && key < lmin) lmin = key;
      }
      uint64_t g = lmin;
      for (int o = 32; o; o >>= 1) {
        uint64_t t2 = __shfl_xor((unsigned long long)g, o);
        if (t2 < g) g = t2;
      }
      if (lane == r) myidx = (uint32_t)g;
      last = g;
    }
  }

  if (lane < KNN) nbr[(size_t)query * KNN + lane] = (uint16_t)myidx;
}

// ================= K2: downstream (round-5-verified numerics; u16 nbr) =================

__global__ __launch_bounds__(K2BLK)
void shot_lrf_kernel(const float* __restrict__ verts,
                     const uint16_t* __restrict__ nbr,
                     float* __restrict__ out) {
  __shared__ float EW[18 * K2BLK];

  const int tid = threadIdx.x;
  const int query = blockIdx.x * K2BLK + tid;
  const int b  = query >> 13;
  const int qi = query & (NPTS - 1);
  const float* vb = verts + (size_t)b * NPTS * 3;

  const float qx = vb[3 * qi + 0], qy = vb[3 * qi + 1], qz = vb[3 * qi + 2];

  uint32_t idxs[KNN];
#pragma unroll
  for (int k = 0; k < KNN; ++k)
    idxs[k] = (uint32_t)nbr[(size_t)query * KNN + k] & (NPTS - 1);

  float radii;
  {
    int i31 = (int)idxs[KNN - 1];
    float dxx = __fsub_rn(vb[3 * i31 + 0], qx);
    float dyy = __fsub_rn(vb[3 * i31 + 1], qy);
    float dzz = __fsub_rn(vb[3 * i31 + 2], qz);
    float d2 = __fadd_rn(__fadd_rn(__fmul_rn(dxx, dxx), __fmul_rn(dyy, dyy)), __fmul_rn(dzz, dzz));
    radii = __fsqrt_rn(fmaxf(d2, 1e-12f));
  }

  float rr[8];
#pragma unroll
  for (int i = 0; i < 8; ++i) rr[i] = 0.0f;
  float l00[4], l10[4], l20[4], l11[4], l21[4], l22[4];
#pragma unroll
  for (int L = 0; L < 4; ++L) { l00[L]=0.0f; l10[L]=0.0f; l20[L]=0.0f; l11[L]=0.0f; l21[L]=0.0f; l22[L]=0.0f; }
#pragma unroll
  for (int c = 0; c < 8; ++c) {
#pragma unroll
    for (int L = 0; L < 4; ++L) {
      int k2 = 4 * c + L;
      int idx = (int)idxs[k2];
      float dxx = __fsub_rn(vb[3 * idx + 0], qx);
      float dyy = __fsub_rn(vb[3 * idx + 1], qy);
      float dzz = __fsub_rn(vb[3 * idx + 2], qz);
      float d2 = __fadd_rn(__fadd_rn(__fmul_rn(dxx, dxx), __fmul_rn(dyy, dyy)), __fmul_rn(dzz, dzz));
      float dist = __fsqrt_rn(fmaxf(d2, 1e-12f));
      float wgt = __fsub_rn(radii, dist);
      rr[k2 & 7] = __fadd_rn(rr[k2 & 7], wgt);
      float wx = __fmul_rn(wgt, dxx), wy = __fmul_rn(wgt, dyy), wz = __fmul_rn(wgt, dzz);
      l00[L] = __fadd_rn(l00[L], __fmul_rn(wx, dxx));
      l10[L] = __fadd_rn(l10[L], __fmul_rn(wy, dxx));
      l20[L] = __fadd_rn(l20[L], __fmul_rn(wz, dxx));
      l11[L] = __fadd_rn(l11[L], __fmul_rn(wy, dyy));
      l21[L] = __fadd_rn(l21[L], __fmul_rn(wz, dyy));
      l22[L] = __fadd_rn(l22[L], __fmul_rn(wz, dzz));
    }
  }
  float c00 = __fadd_rn(__fadd_rn(l00[0], l00[1]), __fadd_rn(l00[2], l00[3]));
  float c10 = __fadd_rn(__fadd_rn(l10[0], l10[1]), __fadd_rn(l10[2], l10[3]));
  float c20 = __fadd_rn(__fadd_rn(l20[0], l20[1]), __fadd_rn(l20[2], l20[3]));
  float c11 = __fadd_rn(__fadd_rn(l11[0], l11[1]), __fadd_rn(l11[2], l11[3]));
  float c21 = __fadd_rn(__fadd_rn(l21[0], l21[1]), __fadd_rn(l21[2], l21[3]));
  float c22 = __fadd_rn(__fadd_rn(l22[0], l22[1]), __fadd_rn(l22[2], l22[3]));
  float sumw = __fadd_rn(
      __fadd_rn(__fadd_rn(rr[0], rr[1]), __fadd_rn(rr[2], rr[3])),
      __fadd_rn(__fadd_rn(rr[4], rr[5]), __fadd_rn(rr[6], rr[7])));

  float a11 = __fdiv_rn(c00, sumw);
  float a21 = __fdiv_rn(c10, sumw);
  float a31 = __fdiv_rn(c20, sumw);
  float a22 = __fdiv_rn(c11, sumw);
  float a32 = __fdiv_rn(c21, sumw);
  float a33 = __fdiv_rn(c22, sumw);

  float* base = &EW[tid];
  float taui, v2;
  {
    float alpha = a21;
    float xnorm = fabsf(a31);
    float beta;
    if (xnorm == 0.0f) {
      taui = 0.0f; v2 = 0.0f; beta = alpha;
      DD(0) = a11; DD(1) = a22; DD(2) = a33;
      EE(0) = beta; EE(1) = a32;
    } else {
      beta = -fsignf(slapy2f(alpha, xnorm), alpha);
      taui = __fdiv_rn(__fsub_rn(beta, alpha), beta);
      float inv = __fdiv_rn(1.0f, __fsub_rn(alpha, beta));
      v2 = __fmul_rn(a31, inv);
      float y1 = __fmul_rn(taui, a22);
      float y2 = __fmul_rn(taui, a32);
      float temp2 = __fmul_rn(a32, v2);
      y1 = __fadd_rn(y1, __fmul_rn(taui, temp2));
      y2 = __fadd_rn(y2, __fmul_rn(__fmul_rn(taui, v2), a33));
      float dot = __fadd_rn(y1, __fmul_rn(y2, v2));
      float aw = __fmul_rn(__fmul_rn(-0.5f, taui), dot);
      float w1 = __fadd_rn(y1, aw);
      float w2 = __fadd_rn(y2, __fmul_rn(aw, v2));
      float a22p = __fadd_rn(__fadd_rn(a22, __fmul_rn(1.0f, -w1)), __fmul_rn(w1, -1.0f));
      float a32p = __fadd_rn(__fadd_rn(a32, __fmul_rn(v2, -w1)), __fmul_rn(w2, -1.0f));
      float a33p = __fadd_rn(__fadd_rn(a33, __fmul_rn(v2, -w2)), __fmul_rn(w2, -v2));
      DD(0) = a11; DD(1) = a22p; DD(2) = a33p;
      EE(0) = beta; EE(1) = a32p;
    }
  }

  for (int i = 0; i < 3; ++i)
    for (int j = 0; j < 3; ++j)
      ZZ(i, j) = (i == j) ? 1.0f : 0.0f;

  steqr3f(base);

  if (taui != 0.0f) {
    for (int j = 0; j < 3; ++j) {
      float wj = __fadd_rn(ZZ(1, j), __fmul_rn(ZZ(2, j), v2));
      float t = __fmul_rn(-taui, wj);
      ZZ(1, j) = __fadd_rn(ZZ(1, j), t);
      ZZ(2, j) = __fadd_rn(ZZ(2, j), __fmul_rn(v2, t));
    }
  }

  float X0 = ZZ(0, 2), X1 = ZZ(1, 2), X2 = ZZ(2, 2);
  float Z0 = ZZ(0, 0), Z1 = ZZ(1, 0), Z2 = ZZ(2, 0);

  int npx = 0, npz = 0;
#pragma unroll
  for (int k2 = 0; k2 < KNN; ++k2) {
    int idx = (int)idxs[k2];
    float dxx = __fsub_rn(vb[3 * idx + 0], qx);
    float dyy = __fsub_rn(vb[3 * idx + 1], qy);
    float dzz = __fsub_rn(vb[3 * idx + 2], qz);
    float px = __fadd_rn(__fadd_rn(__fmul_rn(dxx, X0), __fmul_rn(dyy, X1)), __fmul_rn(dzz, X2));
    float pz = __fadd_rn(__fadd_rn(__fmul_rn(dxx, Z0), __fmul_rn(dyy, Z1)), __fmul_rn(dzz, Z2));
    if (px >= 0.0f) npx++;
    if (pz >= 0.0f) npz++;
  }
  if (2 * npx < KNN) { X0 = -X0; X1 = -X1; X2 = -X2; }
  if (2 * npz < KNN) { Z0 = -Z0; Z1 = -Z1; Z2 = -Z2; }

  float Y0 = __fsub_rn(__fmul_rn(Z1, X2), __fmul_rn(Z2, X1));
  float Y1 = __fsub_rn(__fmul_rn(Z2, X0), __fmul_rn(Z0, X2));
  float Y2 = __fsub_rn(__fmul_rn(Z0, X1), __fmul_rn(Z1, X0));

  float* o = out + (size_t)query * 9;
  o[0] = X0; o[1] = X1; o[2] = X2;
  o[3] = Y0; o[4] = Y1; o[5] = Y2;
  o[6] = Z0; o[7] = Z1; o[8] = Z2;
}

#undef ZZ
#undef DD
#undef EE
#undef CW
#undef SW

extern "C" void kernel_launch(void* const* d_in, const int* in_sizes, int n_in,
                              void* d_out, int out_size, void* d_ws, size_t ws_size,
                              hipStream_t stream) {
  (void)n_in; (void)out_size; (void)ws_size;
  const float* verts = (const float*)d_in[0];
  float* out = (float*)d_out;
  int total = in_sizes[0] / 3;               // 16384 queries

  // ws layout (~1.31 MiB; 2 MiB proven available)
  char* ws = (char*)d_ws;
  uint16_t* nbr    = (uint16_t*)(ws);                               // 1,048,576 B
  uint32_t* cstart = (uint32_t*)(ws + 1048576);                     //   32,772 B (TOTC+1), pad 33,024
  uint32_t* ccnt   = (uint32_t*)(ws + 1048576 + 33024);             //   32,768 B (doubles as cursor)
  float4*   spts   = (float4*)  (ws + 1048576 + 33024 + 32768);     //  262,144 B (16B aligned)

  hipMemsetAsync(ccnt, 0, (size_t)TOTC * 4, stream);
  hist_kernel   <<<total / 256, 256, 0, stream>>>(verts, ccnt);
  scan_kernel   <<<1, 1024, 0, stream>>>(ccnt, cstart);             // also zeroes cursor
  scatter_kernel<<<total / 256, 256, 0, stream>>>(verts, cstart, ccnt, spts);
  knn_select_kernel<<<total / WAVES, BTHR, 0, stream>>>(verts, cstart, spts, nbr);
  shot_lrf_kernel<<<total / K2BLK, K2BLK, 0, stream>>>(verts, nbr, out);
}